// Round 1
// baseline (414.984 us; speedup 1.0000x reference)
//
#include <hip/hip_runtime.h>

#define B_ 2
#define S_ 2048
#define HID_ 1024
#define H_ 16
#define HKV_ 8
#define D_ 128

typedef unsigned short u16;
typedef __attribute__((ext_vector_type(8))) short short8;
typedef __attribute__((ext_vector_type(4))) float f32x4;
typedef __attribute__((ext_vector_type(2))) unsigned short u16x2;
typedef __attribute__((ext_vector_type(4))) unsigned short u16x4;
typedef const __attribute__((address_space(1))) void gvoid;
typedef __attribute__((address_space(3))) void svoid;

__device__ __forceinline__ u16 f2b(float f) {
  union { float f; unsigned u; } v; v.f = f;
  unsigned r = v.u + 0x7FFFu + ((v.u >> 16) & 1u);
  return (u16)(r >> 16);
}

// ---------------- elementwise fp32 -> bf16 ----------------
__global__ __launch_bounds__(256) void conv_bf16_kernel(const float* __restrict__ X,
                                                        u16* __restrict__ Y, int n4) {
  int i = blockIdx.x * 256 + threadIdx.x;
  if (i < n4) {
    const float4 v = ((const float4*)X)[i];
    u16x4 o = { f2b(v.x), f2b(v.y), f2b(v.z), f2b(v.w) };
    ((u16x4*)Y)[i] = o;
  }
}

// ---------------- W [K,N] f32 -> Wt [N,K] bf16 (tiled transpose) ----------------
__global__ __launch_bounds__(256) void transpose_bf16_kernel(const float* __restrict__ W,
                                                             u16* __restrict__ Wt,
                                                             int K, int N) {
  __shared__ float t[32][33];
  const int nb = N >> 5;
  const int bx = blockIdx.x % nb;   // n tile
  const int by = blockIdx.x / nb;   // k tile
  const int tx = threadIdx.x & 31, ty = threadIdx.x >> 5;  // 32 x 8
#pragma unroll
  for (int i = 0; i < 32; i += 8)
    t[ty + i][tx] = W[(size_t)(by * 32 + ty + i) * N + bx * 32 + tx];
  __syncthreads();
#pragma unroll
  for (int i = 0; i < 32; i += 8)
    Wt[(size_t)(bx * 32 + ty + i) * K + by * 32 + tx] = f2b(t[tx][ty + i]);
}

// ---------------- RoPE cos/sin table (fp64 on device, tiny) ----------------
__global__ __launch_bounds__(256) void rope_table_kernel(const int* __restrict__ pid,
                                                         float* __restrict__ ct,
                                                         float* __restrict__ st) {
  int i = blockIdx.x * 256 + threadIdx.x;  // [s][f], f<64
  if (i >= S_ * 64) return;
  int s = i >> 6, f = i & 63;
  double inv = exp2(-(double)f * (19.931568569324174 / 64.0));  // 1e6^(-f/64)
  double ang = (double)pid[s] * inv;
  ct[i] = (float)cos(ang);
  st[i] = (float)sin(ang);
}

// ---------------- GEMM: C[M,N] f32 = A[M,K]bf16 @ Bt[N,K]bf16^T ----------------
// m97 structure: 128x128 tile, BK=32, 4 waves, global_load_lds width 16.
template <int M, int N, int K>
__global__ __launch_bounds__(256) void gemm_bt(const u16* __restrict__ A,
                                               const u16* __restrict__ Bt,
                                               float* __restrict__ C) {
  __shared__ u16 As[128 * 32];
  __shared__ u16 Bs[128 * 32];
  const int tid = threadIdx.x;
  const int w = tid >> 6;
  const int l = tid & 63;
  const int l15 = l & 15, lg = l >> 4;
  const int nbx = N / 128;
  const int bx = blockIdx.x % nbx, by = blockIdx.x / nbx;
  const int row0 = by * 128, col0 = bx * 128;
  const int wr = w >> 1, wc = w & 1;

  f32x4 acc[4][4];
#pragma unroll
  for (int m = 0; m < 4; ++m)
#pragma unroll
    for (int n = 0; n < 4; ++n) acc[m][n] = (f32x4){0.f, 0.f, 0.f, 0.f};

  for (int k0 = 0; k0 < K; k0 += 32) {
    __syncthreads();
#pragma unroll
    for (int i = 0; i < 2; ++i) {
      int c = i * 256 + tid;        // 16B chunk id, 512 total per tile
      int r = c >> 2, cc = c & 3;   // row 0..127, col-chunk 0..3 (8 bf16 each)
      const u16* sa = A + (size_t)(row0 + r) * K + k0 + cc * 8;
      __builtin_amdgcn_global_load_lds((gvoid*)sa, (svoid*)(As + (i * 256 + w * 64) * 8), 16, 0, 0);
      const u16* sb = Bt + (size_t)(col0 + r) * K + k0 + cc * 8;
      __builtin_amdgcn_global_load_lds((gvoid*)sb, (svoid*)(Bs + (i * 256 + w * 64) * 8), 16, 0, 0);
    }
    __syncthreads();
    short8 af[4], bf[4];
#pragma unroll
    for (int m = 0; m < 4; ++m)
      af[m] = *(const short8*)(As + (wr * 64 + m * 16 + l15) * 32 + lg * 8);
#pragma unroll
    for (int n = 0; n < 4; ++n)
      bf[n] = *(const short8*)(Bs + (wc * 64 + n * 16 + l15) * 32 + lg * 8);
#pragma unroll
    for (int m = 0; m < 4; ++m)
#pragma unroll
      for (int n = 0; n < 4; ++n)
        acc[m][n] = __builtin_amdgcn_mfma_f32_16x16x32_bf16(af[m], bf[n], acc[m][n], 0, 0, 0);
  }
#pragma unroll
  for (int m = 0; m < 4; ++m)
#pragma unroll
    for (int n = 0; n < 4; ++n) {
      float* cp = C + (size_t)(row0 + wr * 64 + m * 16 + lg * 4) * N + col0 + wc * 64 + n * 16 + l15;
#pragma unroll
      for (int r = 0; r < 4; ++r) cp[(size_t)r * N] = acc[m][n][r];
    }
}

// ---------------- RMSNorm + RoPE; writes bf16 [B,NH,S,D] (+ optional fp32) ----------------
template <int NH, bool WF>
__global__ __launch_bounds__(256) void norm_rope_kernel(const float* __restrict__ Xf,
                                                        const float* __restrict__ nw,
                                                        const float* __restrict__ ct,
                                                        const float* __restrict__ st,
                                                        u16* __restrict__ Ob,
                                                        float* __restrict__ Of) {
  const int w = threadIdx.x >> 6, l = threadIdx.x & 63;
  const int gid = blockIdx.x * 4 + w;  // row-head index
  const int head = gid % NH, row = gid / NH;
  const int b = row >> 11, s = row & 2047;
  const float* src = Xf + (size_t)row * (NH * 128) + head * 128 + l * 2;
  float x0 = src[0], x1 = src[1];
  float ssum = x0 * x0 + x1 * x1;
#pragma unroll
  for (int d = 1; d < 64; d <<= 1) ssum += __shfl_xor(ssum, d, 64);
  const float sc = rsqrtf(ssum * (1.0f / 128.0f) + 1e-6f);
  const float xn0 = x0 * sc * nw[l * 2];
  const float xn1 = x1 * sc * nw[l * 2 + 1];
  const float y0 = __shfl_xor(xn0, 32, 64);
  const float y1 = __shfl_xor(xn1, 32, 64);
  const int fi = (2 * l) & 63;
  const float c0 = ct[s * 64 + fi], c1 = ct[s * 64 + fi + 1];
  const float s0 = st[s * 64 + fi], s1 = st[s * 64 + fi + 1];
  const float sgn = (l < 32) ? -1.0f : 1.0f;  // rotate_half sign
  const float o0 = xn0 * c0 + sgn * y0 * s0;
  const float o1 = xn1 * c1 + sgn * y1 * s1;
  size_t orow = ((size_t)(b * NH + head) * S_ + s) * 128 + l * 2;
  *(u16x2*)(Ob + orow) = (u16x2){f2b(o0), f2b(o1)};
  if (WF) { Of[orow] = o0; Of[orow + 1] = o1; }
}

// ---------------- V: [B,S,HKV,D] f32 -> [B,HKV,S,D] f32 out + bf16 ----------------
__global__ __launch_bounds__(256) void v_out_kernel(const float* __restrict__ Vf,
                                                    float* __restrict__ vout,
                                                    u16* __restrict__ Vb) {
  int idx = blockIdx.x * 256 + threadIdx.x;
  int d = idx & 127, hkv = (idx >> 7) & 7, row = idx >> 10;
  int b = row >> 11, s = row & 2047;
  float v = Vf[idx];
  size_t o = ((size_t)(b * HKV_ + hkv) * S_ + s) * 128 + d;
  vout[o] = v;
  Vb[o] = f2b(v);
}

// ---------------- flash attention (causal, GQA) ----------------
// grid: B*H*(S/64). block: 256 thr = 4 waves, each wave 16 q-rows. KV tile = 64.
__global__ __launch_bounds__(256) void attn_kernel(const u16* __restrict__ Qb,
                                                   const u16* __restrict__ Kb,
                                                   const u16* __restrict__ Vb,
                                                   u16* __restrict__ Ab) {
  __shared__ u16 Kt[64 * 128];     // K tile, XOR-swizzled (16B granule, row&7)
  __shared__ u16 Vt[128 * 72];     // V^T tile [d][kv], padded stride 72
  __shared__ u16 Pl[4][16 * 72];   // per-wave P, padded stride 72
  const int tid = threadIdx.x;
  const int w = tid >> 6, l = tid & 63;
  const int l15 = l & 15, lg = l >> 4;
  const int bid = blockIdx.x;
  const int qt = bid & 31;
  const int h = (bid >> 5) & 15;
  const int b = bid >> 9;
  const int hkv = h >> 1;  // G = 2
  const int q0 = qt * 64;

  short8 aq[4];
  {
    const u16* qp = Qb + ((size_t)(b * H_ + h) * S_ + q0 + w * 16 + l15) * 128 + lg * 8;
#pragma unroll
    for (int kc = 0; kc < 4; ++kc) aq[kc] = *(const short8*)(qp + kc * 32);
  }
  const u16* Kh = Kb + (size_t)(b * HKV_ + hkv) * S_ * 128;
  const u16* Vh = Vb + (size_t)(b * HKV_ + hkv) * S_ * 128;

  float m_run[4] = {-INFINITY, -INFINITY, -INFINITY, -INFINITY};
  float l_run[4] = {0.f, 0.f, 0.f, 0.f};
  f32x4 oacc[8];
#pragma unroll
  for (int nd = 0; nd < 8; ++nd) oacc[nd] = (f32x4){0.f, 0.f, 0.f, 0.f};
  const float scale = 0.08838834764831845f;  // 1/sqrt(128)

  const int nt = qt + 1;
  for (int kt = 0; kt < nt; ++kt) {
    __syncthreads();
    // stage K tile: 1024 x 16B chunks; source pre-swizzled so swizzled read is conflict-free
#pragma unroll
    for (int i = 0; i < 4; ++i) {
      int c = i * 256 + tid;
      int row = c >> 4, cc = c & 15;
      const u16* src = Kh + (size_t)(kt * 64 + row) * 128 + ((cc ^ (row & 7)) * 8);
      __builtin_amdgcn_global_load_lds((gvoid*)src, (svoid*)(Kt + (i * 256 + w * 64) * 8), 16, 0, 0);
    }
    // stage V transposed (reg-staged, padded => conflict-light)
    {
      int kv = tid >> 2, dg = (tid & 3) * 32;
      const u16* vs = Vh + (size_t)(kt * 64 + kv) * 128 + dg;
#pragma unroll
      for (int cch = 0; cch < 4; ++cch) {
        short8 vv = *(const short8*)(vs + cch * 8);
#pragma unroll
        for (int j = 0; j < 8; ++j) Vt[(dg + cch * 8 + j) * 72 + kv] = (u16)vv[j];
      }
    }
    __syncthreads();
    // QK^T: S[q][kv], q from A(=Q), kv from B(=K rows)
    f32x4 sf[4];
#pragma unroll
    for (int n = 0; n < 4; ++n) sf[n] = (f32x4){0.f, 0.f, 0.f, 0.f};
#pragma unroll
    for (int n = 0; n < 4; ++n) {
      const int row = n * 16 + l15;
#pragma unroll
      for (int kc = 0; kc < 4; ++kc) {
        const int byteoff = row * 256 + (((kc * 32 + lg * 8) * 2) ^ ((row & 7) << 4));
        short8 bk = *(const short8*)((const char*)Kt + byteoff);
        sf[n] = __builtin_amdgcn_mfma_f32_16x16x32_bf16(aq[kc], bk, sf[n], 0, 0, 0);
      }
    }
    // online softmax (per r: one q-row per 16-lane group)
#pragma unroll
    for (int r = 0; r < 4; ++r) {
      const int qg = q0 + w * 16 + lg * 4 + r;
      float sv[4];
      float mx = -INFINITY;
#pragma unroll
      for (int n = 0; n < 4; ++n) {
        float x = sf[n][r] * scale;
        if (kt * 64 + n * 16 + l15 > qg) x = -INFINITY;
        sv[n] = x;
        mx = fmaxf(mx, x);
      }
#pragma unroll
      for (int d = 1; d < 16; d <<= 1) mx = fmaxf(mx, __shfl_xor(mx, d, 64));
      const float mnew = fmaxf(m_run[r], mx);
      const float corr = __expf(m_run[r] - mnew);
      float ls = 0.f;
#pragma unroll
      for (int n = 0; n < 4; ++n) {
        sv[n] = __expf(sv[n] - mnew);
        ls += sv[n];
      }
#pragma unroll
      for (int d = 1; d < 16; d <<= 1) ls += __shfl_xor(ls, d, 64);
      l_run[r] = l_run[r] * corr + ls;
      m_run[r] = mnew;
#pragma unroll
      for (int nd = 0; nd < 8; ++nd) oacc[nd][r] *= corr;
#pragma unroll
      for (int n = 0; n < 4; ++n) Pl[w][(lg * 4 + r) * 72 + n * 16 + l15] = f2b(sv[n]);
    }
    // PV: O[q][d] += P @ V, A=P (rows q), B=V^T rows (cols d)
    short8 ap[2];
#pragma unroll
    for (int k2 = 0; k2 < 2; ++k2)
      ap[k2] = *(const short8*)(&Pl[w][l15 * 72 + k2 * 32 + lg * 8]);
#pragma unroll
    for (int nd = 0; nd < 8; ++nd) {
#pragma unroll
      for (int k2 = 0; k2 < 2; ++k2) {
        short8 bv = *(const short8*)(&Vt[(nd * 16 + l15) * 72 + k2 * 32 + lg * 8]);
        oacc[nd] = __builtin_amdgcn_mfma_f32_16x16x32_bf16(ap[k2], bv, oacc[nd], 0, 0, 0);
      }
    }
  }
  // epilogue: O / l, write bf16 [B,S,H*D]
#pragma unroll
  for (int nd = 0; nd < 8; ++nd) {
#pragma unroll
    for (int r = 0; r < 4; ++r) {
      float val = oacc[nd][r] / l_run[r];
      Ab[((size_t)(b * S_ + q0 + w * 16 + lg * 4 + r)) * 2048 + h * 128 + nd * 16 + l15] = f2b(val);
    }
  }
}

extern "C" void kernel_launch(void* const* d_in, const int* in_sizes, int n_in,
                              void* d_out, int out_size, void* d_ws, size_t ws_size,
                              hipStream_t stream) {
  const float* hs  = (const float*)d_in[0];
  const int*   pid = (const int*)d_in[1];
  const float* Wq  = (const float*)d_in[2];
  const float* Wk  = (const float*)d_in[3];
  const float* Wv  = (const float*)d_in[4];
  const float* Wo  = (const float*)d_in[5];
  const float* qnw = (const float*)d_in[6];
  const float* knw = (const float*)d_in[7];

  float* out0 = (float*)d_out;                          // [B,S,HID]
  float* kout = out0 + (size_t)B_ * HKV_ * S_ * D_;     // [B,HKV,S,D]
  float* vout = kout + (size_t)B_ * HKV_ * S_ * D_;     // [B,HKV,S,D]

  char* ws = (char*)d_ws;
  size_t off = 0;
  auto alloc = [&](size_t bytes) {
    void* p = ws + off;
    off += (bytes + 255) & ~(size_t)255;
    return p;
  };
  u16*   Xb  = (u16*)alloc((size_t)4096 * 1024 * 2);
  u16*   Wqt = (u16*)alloc((size_t)2048 * 1024 * 2);
  u16*   Wkt = (u16*)alloc((size_t)1024 * 1024 * 2);
  u16*   Wvt = (u16*)alloc((size_t)1024 * 1024 * 2);
  u16*   Wot = (u16*)alloc((size_t)1024 * 2048 * 2);
  float* ct  = (float*)alloc((size_t)2048 * 64 * 4);
  float* st  = (float*)alloc((size_t)2048 * 64 * 4);
  float* Qf  = (float*)alloc((size_t)4096 * 2048 * 4);
  float* Kf  = (float*)alloc((size_t)4096 * 1024 * 4);
  float* Vf  = (float*)alloc((size_t)4096 * 1024 * 4);
  u16*   Qb  = (u16*)alloc((size_t)B_ * H_ * S_ * D_ * 2);
  u16*   Kb  = (u16*)alloc((size_t)B_ * HKV_ * S_ * D_ * 2);
  u16*   Vb  = (u16*)alloc((size_t)B_ * HKV_ * S_ * D_ * 2);
  u16*   Ab  = (u16*)Qf;  // alias: Qf dead after norm_rope; Ab needs 16MB <= 32MB

  // 1) conversions
  conv_bf16_kernel<<<4096, 256, 0, stream>>>(hs, Xb, 4096 * 1024 / 4);
  transpose_bf16_kernel<<<(1024 / 32) * (2048 / 32), 256, 0, stream>>>(Wq, Wqt, 1024, 2048);
  transpose_bf16_kernel<<<(1024 / 32) * (1024 / 32), 256, 0, stream>>>(Wk, Wkt, 1024, 1024);
  transpose_bf16_kernel<<<(1024 / 32) * (1024 / 32), 256, 0, stream>>>(Wv, Wvt, 1024, 1024);
  transpose_bf16_kernel<<<(2048 / 32) * (1024 / 32), 256, 0, stream>>>(Wo, Wot, 2048, 1024);
  rope_table_kernel<<<512, 256, 0, stream>>>(pid, ct, st);

  // 2) QKV projections
  gemm_bt<4096, 2048, 1024><<<32 * 16, 256, 0, stream>>>(Xb, Wqt, Qf);
  gemm_bt<4096, 1024, 1024><<<32 * 8, 256, 0, stream>>>(Xb, Wkt, Kf);
  gemm_bt<4096, 1024, 1024><<<32 * 8, 256, 0, stream>>>(Xb, Wvt, Vf);

  // 3) norm + rope (+ k fp32 out), v rearrange (+ v fp32 out)
  norm_rope_kernel<16, false><<<16384, 256, 0, stream>>>(Qf, qnw, ct, st, Qb, nullptr);
  norm_rope_kernel<8, true><<<8192, 256, 0, stream>>>(Kf, knw, ct, st, Kb, kout);
  v_out_kernel<<<16384, 256, 0, stream>>>(Vf, vout, Vb);

  // 4) attention
  attn_kernel<<<B_ * H_ * (S_ / 64), 256, 0, stream>>>(Qb, Kb, Vb, Ab);

  // 5) output projection -> d_out
  gemm_bt<4096, 1024, 2048><<<32 * 8, 256, 0, stream>>>(Ab, Wot, out0);
}

// Round 4
// 261.372 us; speedup vs baseline: 1.5877x; 1.5877x over previous
//
#include <hip/hip_runtime.h>

#define B_ 2
#define S_ 2048
#define HID_ 1024
#define H_ 16
#define HKV_ 8
#define D_ 128

typedef unsigned short u16;
typedef __attribute__((ext_vector_type(8))) short short8;
typedef __attribute__((ext_vector_type(4))) float f32x4;
typedef __attribute__((ext_vector_type(16))) float f32x16;
typedef __attribute__((ext_vector_type(2))) unsigned short u16x2;
typedef __attribute__((ext_vector_type(4))) unsigned short u16x4;
typedef const __attribute__((address_space(1))) void gvoid;
typedef __attribute__((address_space(3))) void svoid;

__device__ __forceinline__ u16 f2b(float f) {
  union { float f; unsigned u; } v; v.f = f;
  unsigned r = v.u + 0x7FFFu + ((v.u >> 16) & 1u);
  return (u16)(r >> 16);
}

__device__ __forceinline__ float exp2_fast(float x) {
  float r; asm("v_exp_f32 %0, %1" : "=v"(r) : "v"(x)); return r;
}
__device__ __forceinline__ unsigned cvtpk_bf16(float lo, float hi) {
  unsigned r; asm("v_cvt_pk_bf16_f32 %0, %1, %2" : "=v"(r) : "v"(lo), "v"(hi)); return r;
}
// explicit drain of async global_load_lds before a barrier (T3 recipe; m152 discipline)
__device__ __forceinline__ void vm_drain() {
  asm volatile("s_waitcnt vmcnt(0)" ::: "memory");
  __builtin_amdgcn_sched_barrier(0);
}

// ---------------- elementwise fp32 -> bf16 ----------------
__global__ __launch_bounds__(256) void conv_bf16_kernel(const float* __restrict__ X,
                                                        u16* __restrict__ Y, int n4) {
  int i = blockIdx.x * 256 + threadIdx.x;
  if (i < n4) {
    const float4 v = ((const float4*)X)[i];
    u16x4 o = { f2b(v.x), f2b(v.y), f2b(v.z), f2b(v.w) };
    ((u16x4*)Y)[i] = o;
  }
}

// ---------------- W [K,N] f32 -> Wt [N,K] bf16 (tiled transpose) ----------------
__global__ __launch_bounds__(256) void transpose_bf16_kernel(const float* __restrict__ W,
                                                             u16* __restrict__ Wt,
                                                             int K, int N) {
  __shared__ float t[32][33];
  const int nb = N >> 5;
  const int bx = blockIdx.x % nb;
  const int by = blockIdx.x / nb;
  const int tx = threadIdx.x & 31, ty = threadIdx.x >> 5;
#pragma unroll
  for (int i = 0; i < 32; i += 8)
    t[ty + i][tx] = W[(size_t)(by * 32 + ty + i) * N + bx * 32 + tx];
  __syncthreads();
#pragma unroll
  for (int i = 0; i < 32; i += 8)
    Wt[(size_t)(bx * 32 + ty + i) * K + by * 32 + tx] = f2b(t[tx][ty + i]);
}

// ---------------- RoPE cos/sin table ----------------
__global__ __launch_bounds__(256) void rope_table_kernel(const int* __restrict__ pid,
                                                         float* __restrict__ ct,
                                                         float* __restrict__ st) {
  int i = blockIdx.x * 256 + threadIdx.x;
  if (i >= S_ * 64) return;
  int s = i >> 6, f = i & 63;
  double inv = exp2(-(double)f * (19.931568569324174 / 64.0));
  double ang = (double)pid[s] * inv;
  ct[i] = (float)cos(ang);
  st[i] = (float)sin(ang);
}

// ---------------- GEMM: C[M,N] f32 = A[M,K]bf16 @ Bt[N,K]bf16^T ----------------
template <int M, int N, int K>
__global__ __launch_bounds__(256) void gemm_bt(const u16* __restrict__ A,
                                               const u16* __restrict__ Bt,
                                               float* __restrict__ C) {
  __shared__ u16 As[128 * 32];
  __shared__ u16 Bs[128 * 32];
  const int tid = threadIdx.x;
  const int w = tid >> 6;
  const int l = tid & 63;
  const int l15 = l & 15, lg = l >> 4;
  const int nbx = N / 128;
  const int bx = blockIdx.x % nbx, by = blockIdx.x / nbx;
  const int row0 = by * 128, col0 = bx * 128;
  const int wr = w >> 1, wc = w & 1;

  f32x4 acc[4][4];
#pragma unroll
  for (int m = 0; m < 4; ++m)
#pragma unroll
    for (int n = 0; n < 4; ++n) acc[m][n] = (f32x4){0.f, 0.f, 0.f, 0.f};

  for (int k0 = 0; k0 < K; k0 += 32) {
    __syncthreads();
#pragma unroll
    for (int i = 0; i < 2; ++i) {
      int c = i * 256 + tid;
      int r = c >> 2, cc = c & 3;
      const u16* sa = A + (size_t)(row0 + r) * K + k0 + cc * 8;
      __builtin_amdgcn_global_load_lds((gvoid*)sa, (svoid*)(As + (i * 256 + w * 64) * 8), 16, 0, 0);
      const u16* sb = Bt + (size_t)(col0 + r) * K + k0 + cc * 8;
      __builtin_amdgcn_global_load_lds((gvoid*)sb, (svoid*)(Bs + (i * 256 + w * 64) * 8), 16, 0, 0);
    }
    vm_drain();
    __syncthreads();
    short8 af[4], bf[4];
#pragma unroll
    for (int m = 0; m < 4; ++m)
      af[m] = *(const short8*)(As + (wr * 64 + m * 16 + l15) * 32 + lg * 8);
#pragma unroll
    for (int n = 0; n < 4; ++n)
      bf[n] = *(const short8*)(Bs + (wc * 64 + n * 16 + l15) * 32 + lg * 8);
#pragma unroll
    for (int m = 0; m < 4; ++m)
#pragma unroll
      for (int n = 0; n < 4; ++n)
        acc[m][n] = __builtin_amdgcn_mfma_f32_16x16x32_bf16(af[m], bf[n], acc[m][n], 0, 0, 0);
  }
#pragma unroll
  for (int m = 0; m < 4; ++m)
#pragma unroll
    for (int n = 0; n < 4; ++n) {
      float* cp = C + (size_t)(row0 + wr * 64 + m * 16 + lg * 4) * N + col0 + wc * 64 + n * 16 + l15;
#pragma unroll
      for (int r = 0; r < 4; ++r) cp[(size_t)r * N] = acc[m][n][r];
    }
}

// ---------------- RMSNorm + RoPE; writes bf16 [B,NH,S,D] (+ optional fp32) ----------------
template <int NH, bool WF>
__global__ __launch_bounds__(256) void norm_rope_kernel(const float* __restrict__ Xf,
                                                        const float* __restrict__ nw,
                                                        const float* __restrict__ ct,
                                                        const float* __restrict__ st,
                                                        u16* __restrict__ Ob,
                                                        float* __restrict__ Of) {
  const int w = threadIdx.x >> 6, l = threadIdx.x & 63;
  const int gid = blockIdx.x * 4 + w;
  const int head = gid % NH, row = gid / NH;
  const int b = row >> 11, s = row & 2047;
  const float* src = Xf + (size_t)row * (NH * 128) + head * 128 + l * 2;
  float x0 = src[0], x1 = src[1];
  float ssum = x0 * x0 + x1 * x1;
#pragma unroll
  for (int d = 1; d < 64; d <<= 1) ssum += __shfl_xor(ssum, d, 64);
  const float sc = rsqrtf(ssum * (1.0f / 128.0f) + 1e-6f);
  const float xn0 = x0 * sc * nw[l * 2];
  const float xn1 = x1 * sc * nw[l * 2 + 1];
  const float y0 = __shfl_xor(xn0, 32, 64);
  const float y1 = __shfl_xor(xn1, 32, 64);
  const int fi = (2 * l) & 63;
  const float c0 = ct[s * 64 + fi], c1 = ct[s * 64 + fi + 1];
  const float s0 = st[s * 64 + fi], s1 = st[s * 64 + fi + 1];
  const float sgn = (l < 32) ? -1.0f : 1.0f;
  const float o0 = xn0 * c0 + sgn * y0 * s0;
  const float o1 = xn1 * c1 + sgn * y1 * s1;
  size_t orow = ((size_t)(b * NH + head) * S_ + s) * 128 + l * 2;
  *(u16x2*)(Ob + orow) = (u16x2){f2b(o0), f2b(o1)};
  if (WF) { Of[orow] = o0; Of[orow + 1] = o1; }
}

// ---------------- V: [B,S,HKV,D] f32 -> vout [B,HKV,S,D] f32 + VT [B,HKV,D,S] bf16 ----------------
__global__ __launch_bounds__(256) void vtrans_kernel(const float* __restrict__ Vf,
                                                     float* __restrict__ vout,
                                                     u16* __restrict__ VTb) {
  __shared__ float t[32][33];
  const int bid = blockIdx.x;
  const int stile = bid & 63;
  const int dt = (bid >> 6) & 3;
  const int bh = bid >> 8;
  const int b = bh >> 3, hkv = bh & 7;
  const int tx = threadIdx.x & 31, ty = threadIdx.x >> 5;
#pragma unroll
  for (int j = 0; j < 4; ++j) {
    int s = stile * 32 + ty + 8 * j;
    t[ty + 8 * j][tx] = Vf[((size_t)(b * 2048 + s) * 8 + hkv) * 128 + dt * 32 + tx];
  }
  __syncthreads();
#pragma unroll
  for (int j = 0; j < 4; ++j) {
    int s = stile * 32 + ty + 8 * j;
    vout[((size_t)(b * 8 + hkv) * 2048 + s) * 128 + dt * 32 + tx] = t[ty + 8 * j][tx];
    int d = dt * 32 + ty + 8 * j;
    VTb[((size_t)(b * 8 + hkv) * 128 + d) * 2048 + stile * 32 + tx] = f2b(t[tx][ty + 8 * j]);
  }
}

// ---------------- flash attention (causal, GQA), 32x32 swapped-QK ----------------
// grid: B*H*8 pair-blocks; block 256 thr = 4 waves * 32 q rows = 128-row panel.
// Each block does panel pp and panel 15-pp (constant work). KV tile = 64.
__global__ __launch_bounds__(256) void attn_kernel(const u16* __restrict__ Qb,
                                                   const u16* __restrict__ Kb,
                                                   const u16* __restrict__ VTb,
                                                   u16* __restrict__ Ab) {
  __shared__ u16 lds[2][16384];  // per buf: K tile [64][128] + VT tile [128][64]
  const int tid = threadIdx.x;
  const int w = tid >> 6, l = tid & 63;
  const int l31 = l & 31, hi = l >> 5;
  const int bid = blockIdx.x;
  const int pp0 = bid & 7;
  const int hh = (bid >> 3) & 15;
  const int b = bid >> 7;
  const int hkv = hh >> 1;

  const u16* Kh = Kb + (size_t)(b * HKV_ + hkv) * S_ * 128;
  const u16* VTh = VTb + (size_t)(b * HKV_ + hkv) * 128 * S_;
  const float KSC = 0.12751740027f;  // (1/sqrt(128)) * log2(e)

  for (int halfp = 0; halfp < 2; ++halfp) {
    const int pp = halfp ? (15 - pp0) : pp0;
    const int q0 = pp * 128;
    const int nt = 2 * (pp + 1);
    const int qrow = q0 + w * 32 + l31;  // this lane's q (col index)

    // Q fragments in registers: k = 16c + 8*hi + j
    short8 qf[8];
    {
      const u16* qp = Qb + ((size_t)(b * H_ + hh) * S_ + qrow) * 128 + hi * 8;
#pragma unroll
      for (int c = 0; c < 8; ++c) qf[c] = *(const short8*)(qp + c * 16);
    }

    float m_run = -1e30f, l_run = 0.f;
    f32x16 oacc[4];
#pragma unroll
    for (int n = 0; n < 4; ++n)
#pragma unroll
      for (int r = 0; r < 16; ++r) oacc[n][r] = 0.f;

    // ---- staging helper (8 global_load_lds per thread; LDS dest wave-uniform) ----
    auto stage = [&](int kt, int buf) {
      const u16* Kp = Kh + (size_t)kt * 64 * 128;
      const u16* Vp = VTh + kt * 64;
      u16* Kd = &lds[buf][0];
      u16* Vd = &lds[buf][8192];
#pragma unroll
      for (int i = 0; i < 4; ++i) {
        int c = i * 256 + tid;
        int kr = c >> 4, kc = c & 15;  // K: 64 rows x 16 chunks of 16B
        __builtin_amdgcn_global_load_lds((gvoid*)(Kp + kr * 128 + ((kc ^ (kr & 7)) * 8)),
                                         (svoid*)(Kd + (i * 256 + w * 64) * 8), 16, 0, 0);
        int vd = c >> 3, vc = c & 7;   // VT: 128 rows x 8 chunks of 16B
        __builtin_amdgcn_global_load_lds((gvoid*)(Vp + (size_t)vd * S_ + ((vc ^ (vd & 7)) * 8)),
                                         (svoid*)(Vd + (i * 256 + w * 64) * 8), 16, 0, 0);
      }
    };

    stage(0, 0);
    vm_drain();
    __syncthreads();
    int cur = 0;
    for (int kt = 0; kt < nt; ++kt) {
      if (kt + 1 < nt) stage(kt + 1, cur ^ 1);
      const u16* Kl = &lds[cur][0];
      const u16* Vl = &lds[cur][8192];

      // ---- QK^T (swapped): st_[t] = K(32kv) x Q(32q)^T, col=q, rows=kv ----
      f32x16 st_[2];
#pragma unroll
      for (int t = 0; t < 2; ++t) {
#pragma unroll
        for (int r = 0; r < 16; ++r) st_[t][r] = 0.f;
        const int row = t * 32 + l31;
        const int rb = row * 256, sw = (row & 7) << 4;
#pragma unroll
        for (int c = 0; c < 8; ++c) {
          short8 kf = *(const short8*)((const char*)Kl + rb + ((c * 32 + hi * 16) ^ sw));
          st_[t] = __builtin_amdgcn_mfma_f32_32x32x16_bf16(kf, qf[c], st_[t], 0, 0, 0);
        }
      }

      // ---- softmax (lane-local, base-2 domain) ----
      float pv[2][16];
      float mx = -1e30f;
      const bool domask = (kt >= nt - 2);
#pragma unroll
      for (int t = 0; t < 2; ++t)
#pragma unroll
        for (int r = 0; r < 16; ++r) {
          float x = st_[t][r] * KSC;
          if (domask) {
            int kv = kt * 64 + t * 32 + (r & 3) + 8 * (r >> 2) + 4 * hi;
            if (kv > qrow) x = -1e30f;
          }
          pv[t][r] = x;
          mx = fmaxf(mx, x);
        }
      mx = fmaxf(mx, __shfl_xor(mx, 32, 64));  // pair-reduce (q duplicated on l, l^32)

      if (__any(mx > m_run + 8.0f)) {  // rescale (rare after first tile)
        float mnew = fmaxf(m_run, mx);
        float corr = exp2_fast(m_run - mnew);
        l_run *= corr;
        m_run = mnew;
#pragma unroll
        for (int r = 0; r < 16; ++r) {
          float cr = __shfl(corr, (r & 3) + 8 * (r >> 2) + 4 * hi, 64);
#pragma unroll
          for (int n = 0; n < 4; ++n) oacc[n][r] *= cr;
        }
      }

      float ls = 0.f;
#pragma unroll
      for (int t = 0; t < 2; ++t)
#pragma unroll
        for (int r = 0; r < 16; ++r) {
          float p = exp2_fast(pv[t][r] - m_run);
          pv[t][r] = p;
          ls += p;
        }
      l_run += ls + __shfl_xor(ls, 32, 64);

      // ---- P -> bf16 A-fragments (cvt_pk + shfl_xor(32) + hi-select) ----
      // pv[t][r] = P[q][kv = t*32 + (r&3) + 8*(r>>2) + 4*hi]
      // fragment cp=(t,cc) word wi on lane: kv = cp*16 + 8*hi + 2*wi + {0,1}
      unsigned paw[4][4];
#pragma unroll
      for (int t = 0; t < 2; ++t) {
        unsigned W[4][2], Wx[4][2];
#pragma unroll
        for (int g = 0; g < 4; ++g)
#pragma unroll
          for (int i = 0; i < 2; ++i) {
            W[g][i] = cvtpk_bf16(pv[t][4 * g + 2 * i], pv[t][4 * g + 2 * i + 1]);
            Wx[g][i] = __shfl_xor(W[g][i], 32, 64);
          }
#pragma unroll
        for (int cc = 0; cc < 2; ++cc) {
          paw[t * 2 + cc][0] = hi ? Wx[2 * cc + 1][0] : W[2 * cc][0];
          paw[t * 2 + cc][1] = hi ? Wx[2 * cc + 1][1] : W[2 * cc][1];
          paw[t * 2 + cc][2] = hi ? W[2 * cc + 1][0] : Wx[2 * cc][0];
          paw[t * 2 + cc][3] = hi ? W[2 * cc + 1][1] : Wx[2 * cc][1];
        }
      }

      // ---- PV: oacc[n] += P(32q x 16kv) x VT(32d x 16kv)^T ----
#pragma unroll
      for (int cp = 0; cp < 4; ++cp) {
        short8 paf;
        ((unsigned*)&paf)[0] = paw[cp][0];
        ((unsigned*)&paf)[1] = paw[cp][1];
        ((unsigned*)&paf)[2] = paw[cp][2];
        ((unsigned*)&paf)[3] = paw[cp][3];
#pragma unroll
        for (int n = 0; n < 4; ++n) {
          const int d = n * 32 + l31;
          short8 vf = *(const short8*)((const char*)Vl + d * 128 + ((cp * 32 + hi * 16) ^ ((d & 7) << 4)));
          oacc[n] = __builtin_amdgcn_mfma_f32_32x32x16_bf16(paf, vf, oacc[n], 0, 0, 0);
        }
      }
      vm_drain();
      __syncthreads();
      cur ^= 1;
    }

    // ---- epilogue: normalize, write bf16 [B,S,H*D] ----
#pragma unroll
    for (int r = 0; r < 16; ++r) {
      const int ql = (r & 3) + 8 * (r >> 2) + 4 * hi;
      float lb = __shfl(l_run, ql, 64);
      float inv = 1.0f / lb;
      const int q = q0 + w * 32 + ql;
      u16* op = Ab + ((size_t)(b * S_) + q) * 2048 + hh * 128 + l31;
#pragma unroll
      for (int n = 0; n < 4; ++n) op[n * 32] = f2b(oacc[n][r] * inv);
    }
  }
}

extern "C" void kernel_launch(void* const* d_in, const int* in_sizes, int n_in,
                              void* d_out, int out_size, void* d_ws, size_t ws_size,
                              hipStream_t stream) {
  const float* hs  = (const float*)d_in[0];
  const int*   pid = (const int*)d_in[1];
  const float* Wq  = (const float*)d_in[2];
  const float* Wk  = (const float*)d_in[3];
  const float* Wv  = (const float*)d_in[4];
  const float* Wo  = (const float*)d_in[5];
  const float* qnw = (const float*)d_in[6];
  const float* knw = (const float*)d_in[7];

  float* out0 = (float*)d_out;
  float* kout = out0 + (size_t)B_ * HKV_ * S_ * D_;
  float* vout = kout + (size_t)B_ * HKV_ * S_ * D_;

  char* ws = (char*)d_ws;
  size_t off = 0;
  auto alloc = [&](size_t bytes) {
    void* p = ws + off;
    off += (bytes + 255) & ~(size_t)255;
    return p;
  };
  u16*   Xb  = (u16*)alloc((size_t)4096 * 1024 * 2);
  u16*   Wqt = (u16*)alloc((size_t)2048 * 1024 * 2);
  u16*   Wkt = (u16*)alloc((size_t)1024 * 1024 * 2);
  u16*   Wvt = (u16*)alloc((size_t)1024 * 1024 * 2);
  u16*   Wot = (u16*)alloc((size_t)1024 * 2048 * 2);
  float* ct  = (float*)alloc((size_t)2048 * 64 * 4);
  float* st  = (float*)alloc((size_t)2048 * 64 * 4);
  float* Qf  = (float*)alloc((size_t)4096 * 2048 * 4);
  float* Kf  = (float*)alloc((size_t)4096 * 1024 * 4);
  float* Vf  = (float*)alloc((size_t)4096 * 1024 * 4);
  u16*   Qbb = (u16*)alloc((size_t)B_ * H_ * S_ * D_ * 2);
  u16*   Kbb = (u16*)alloc((size_t)B_ * HKV_ * S_ * D_ * 2);
  u16*   VTb = (u16*)alloc((size_t)B_ * HKV_ * D_ * S_ * 2);
  u16*   Ab  = (u16*)Qf;  // alias: Qf dead after norm_rope; Ab 16MB <= 32MB

  conv_bf16_kernel<<<4096, 256, 0, stream>>>(hs, Xb, 4096 * 1024 / 4);
  transpose_bf16_kernel<<<(1024 / 32) * (2048 / 32), 256, 0, stream>>>(Wq, Wqt, 1024, 2048);
  transpose_bf16_kernel<<<(1024 / 32) * (1024 / 32), 256, 0, stream>>>(Wk, Wkt, 1024, 1024);
  transpose_bf16_kernel<<<(1024 / 32) * (1024 / 32), 256, 0, stream>>>(Wv, Wvt, 1024, 1024);
  transpose_bf16_kernel<<<(2048 / 32) * (1024 / 32), 256, 0, stream>>>(Wo, Wot, 2048, 1024);
  rope_table_kernel<<<512, 256, 0, stream>>>(pid, ct, st);

  gemm_bt<4096, 2048, 1024><<<32 * 16, 256, 0, stream>>>(Xb, Wqt, Qf);
  gemm_bt<4096, 1024, 1024><<<32 * 8, 256, 0, stream>>>(Xb, Wkt, Kf);
  gemm_bt<4096, 1024, 1024><<<32 * 8, 256, 0, stream>>>(Xb, Wvt, Vf);

  norm_rope_kernel<16, false><<<16384, 256, 0, stream>>>(Qf, qnw, ct, st, Qbb, nullptr);
  norm_rope_kernel<8, true><<<8192, 256, 0, stream>>>(Kf, knw, ct, st, Kbb, kout);
  vtrans_kernel<<<4096, 256, 0, stream>>>(Vf, vout, VTb);

  attn_kernel<<<256, 256, 0, stream>>>(Qbb, Kbb, VTb, Ab);

  gemm_bt<4096, 1024, 2048><<<32 * 8, 256, 0, stream>>>(Ab, Wot, out0);
}